// Round 8
// baseline (464.854 us; speedup 1.0000x reference)
//
#include <hip/hip_runtime.h>
#include <hip/hip_bf16.h>

#define N_NODES 100000
#define N_EDGES 1600000
#define D_IN 256
#define D_OUT 128

typedef short bf16x8 __attribute__((ext_vector_type(8)));
typedef float f32x4 __attribute__((ext_vector_type(4)));

__device__ __forceinline__ unsigned short f2bf(float f) {
    unsigned int u = __builtin_bit_cast(unsigned int, f);
    u += 0x7fffu + ((u >> 16) & 1u);   // round-to-nearest-even
    return (unsigned short)(u >> 16);
}
__device__ __forceinline__ float bf_lo(unsigned int h) {
    return __builtin_bit_cast(float, h << 16);
}
__device__ __forceinline__ float bf_hi(unsigned int h) {
    return __builtin_bit_cast(float, h & 0xffff0000u);
}

// ---------- W transpose+convert: WbT[n][k] = bf16(W[k][n]) ----------
__global__ __launch_bounds__(256) void convert_w(const float* __restrict__ W,
                                                 unsigned short* __restrict__ WbT) {
    int i = blockIdx.x * 256 + threadIdx.x;      // 32768 total
    int k = i >> 7;
    int n = i & 127;
    WbT[(size_t)n * D_IN + k] = f2bf(W[i]);
}

// ---------- GEMM: hb = bf16(x @ W), MFMA 16x16x32 ----------
// wave does 32 rows x 128 cols (two A-frags share every B-frag).
__global__ __launch_bounds__(256) void gemm_mfma(const float* __restrict__ x,
                                                 const unsigned short* __restrict__ WbT,
                                                 unsigned short* __restrict__ hb) {
    const int wave = threadIdx.x >> 6;
    const int lane = threadIdx.x & 63;
    const int row0 = blockIdx.x * 128 + wave * 32;
    if (row0 >= N_NODES) return;                 // wave-uniform (100000 % 32 == 0)
    const int m = lane & 15;
    const int q = lane >> 4;

    const float* xr0 = x + (size_t)(row0 + m) * D_IN;
    const float* xr1 = x + (size_t)(row0 + 16 + m) * D_IN;

    f32x4 acc[2][8];
#pragma unroll
    for (int h = 0; h < 2; ++h)
#pragma unroll
        for (int nt = 0; nt < 8; ++nt) acc[h][nt] = (f32x4){0.f, 0.f, 0.f, 0.f};

#pragma unroll
    for (int kc = 0; kc < 8; ++kc) {
        const int kb = kc * 32 + q * 8;
        float4 a00 = *(const float4*)(xr0 + kb);
        float4 a01 = *(const float4*)(xr0 + kb + 4);
        float4 a10 = *(const float4*)(xr1 + kb);
        float4 a11 = *(const float4*)(xr1 + kb + 4);
        bf16x8 af0, af1;
        af0[0] = (short)f2bf(a00.x); af0[1] = (short)f2bf(a00.y);
        af0[2] = (short)f2bf(a00.z); af0[3] = (short)f2bf(a00.w);
        af0[4] = (short)f2bf(a01.x); af0[5] = (short)f2bf(a01.y);
        af0[6] = (short)f2bf(a01.z); af0[7] = (short)f2bf(a01.w);
        af1[0] = (short)f2bf(a10.x); af1[1] = (short)f2bf(a10.y);
        af1[2] = (short)f2bf(a10.z); af1[3] = (short)f2bf(a10.w);
        af1[4] = (short)f2bf(a11.x); af1[5] = (short)f2bf(a11.y);
        af1[6] = (short)f2bf(a11.z); af1[7] = (short)f2bf(a11.w);
#pragma unroll
        for (int nt = 0; nt < 8; ++nt) {
            bf16x8 bf = *(const bf16x8*)(WbT + (size_t)(nt * 16 + m) * D_IN + kb);
            acc[0][nt] = __builtin_amdgcn_mfma_f32_16x16x32_bf16(af0, bf, acc[0][nt], 0, 0, 0);
            acc[1][nt] = __builtin_amdgcn_mfma_f32_16x16x32_bf16(af1, bf, acc[1][nt], 0, 0, 0);
        }
    }

    // D layout: row = q*4 + r, col = nt*16 + m
#pragma unroll
    for (int h = 0; h < 2; ++h)
#pragma unroll
        for (int nt = 0; nt < 8; ++nt)
#pragma unroll
            for (int r = 0; r < 4; ++r) {
                int grow = row0 + h * 16 + q * 4 + r;
                hb[(size_t)grow * D_OUT + nt * 16 + m] = f2bf(acc[h][nt][r]);
            }
}

// ---------- histogram of rows ----------
__global__ __launch_bounds__(256) void hist_rows(const int* __restrict__ rows,
                                                 int* __restrict__ counts) {
    int i = blockIdx.x * 256 + threadIdx.x;
    if (i < N_EDGES / 4) {
        int4 r = *(const int4*)(rows + i * 4);
        atomicAdd(&counts[r.x], 1);
        atomicAdd(&counts[r.y], 1);
        atomicAdd(&counts[r.z], 1);
        atomicAdd(&counts[r.w], 1);
    }
}

// ---------- hierarchical scan ----------
#define SCHUNK 1024
__global__ __launch_bounds__(1024) void scan_reduce(const int* __restrict__ counts,
                                                    int* __restrict__ bsum, int n) {
    __shared__ int ws[16];
    const int t = threadIdx.x, lane = t & 63, wid = t >> 6;
    int i = blockIdx.x * SCHUNK + t;
    int v = (i < n) ? counts[i] : 0;
#pragma unroll
    for (int off = 32; off >= 1; off >>= 1) v += __shfl_down(v, off);
    if (lane == 0) ws[wid] = v;
    __syncthreads();
    if (t == 0) {
        int s = 0;
#pragma unroll
        for (int w = 0; w < 16; ++w) s += ws[w];
        bsum[blockIdx.x] = s;
    }
}

__global__ __launch_bounds__(64) void scan_bsums(int* __restrict__ bsum, int nb) {
    const int lane = threadIdx.x;
    int carry = 0;
    for (int base = 0; base < nb; base += 64) {
        int i = base + lane;
        int v = (i < nb) ? bsum[i] : 0;
        int x = v;
#pragma unroll
        for (int off = 1; off < 64; off <<= 1) {
            int u = __shfl_up(x, off);
            if (lane >= off) x += u;
        }
        if (i < nb) bsum[i] = x - v + carry;
        carry += __shfl(x, 63);
    }
}

__global__ __launch_bounds__(1024) void scan_apply(const int* __restrict__ counts,
                                                   const int* __restrict__ bsum,
                                                   int* __restrict__ ptr,
                                                   int* __restrict__ cursor, int n) {
    __shared__ int wtot[16];
    const int t = threadIdx.x, lane = t & 63, wid = t >> 6;
    int i = blockIdx.x * SCHUNK + t;
    int v = (i < n) ? counts[i] : 0;
    int x = v;
#pragma unroll
    for (int off = 1; off < 64; off <<= 1) {
        int u = __shfl_up(x, off);
        if (lane >= off) x += u;
    }
    if (lane == 63) wtot[wid] = x;
    __syncthreads();
    if (wid == 0) {
        int wv = (lane < 16) ? wtot[lane] : 0;
        int y = wv;
#pragma unroll
        for (int off = 1; off < 16; off <<= 1) {
            int u = __shfl_up(y, off);
            if (lane >= off) y += u;
        }
        if (lane < 16) wtot[lane] = y - wv;
    }
    __syncthreads();
    int excl = (x - v) + wtot[wid] + bsum[blockIdx.x];
    if (i < n) {
        ptr[i] = excl;
        cursor[i] = excl;
        if (i == n - 1) ptr[n] = excl + v;
    }
}

// ---------- permute: 1 edge/thread, packed int2 store ----------
// 1 edge/thread: occupancy/MLP (proven R2); packed int2: one dirtied
// line per edge (proven R3). HIP int2 type, no ext_vector in signature,
// no nontemporal (R5/R6/R7 failures).
__global__ __launch_bounds__(256) void permute_edges(const int* __restrict__ rows,
                                                     const int* __restrict__ cols,
                                                     const float* __restrict__ vals,
                                                     int* __restrict__ cursor,
                                                     int2* __restrict__ edge_r) {
    int e = blockIdx.x * 256 + threadIdx.x;
    if (e < N_EDGES) {
        int r = rows[e];
        int c = cols[e];
        float v = vals[e];
        int pos = atomicAdd(&cursor[r], 1);
        edge_r[pos] = make_int2(c, __builtin_bit_cast(int, v));
    }
}

// ---------- gather: out[row] = relu(sum v * hb[c]), 4-way edge ILP ----------
__global__ __launch_bounds__(256) void gather_rows(const int* __restrict__ ptr,
                                                   const int2* __restrict__ edge_r,
                                                   const unsigned short* __restrict__ hb,
                                                   float* __restrict__ out) {
    int row  = blockIdx.x * 4 + (threadIdx.x >> 6);
    int lane = threadIdx.x & 63;
    if (row >= N_NODES) return;
    // row is wave-uniform -> force bounds into SGPRs (edge loads become scalar)
    int beg = __builtin_amdgcn_readfirstlane(ptr[row]);
    int end = __builtin_amdgcn_readfirstlane(ptr[row + 1]);

    float ax0 = 0.f, ay0 = 0.f, ax1 = 0.f, ay1 = 0.f;
    float ax2 = 0.f, ay2 = 0.f, ax3 = 0.f, ay3 = 0.f;
    int j = beg;
    for (; j + 4 <= end; j += 4) {
        int2 e0 = edge_r[j + 0];
        int2 e1 = edge_r[j + 1];
        int2 e2 = edge_r[j + 2];
        int2 e3 = edge_r[j + 3];
        unsigned int h0 = *(const unsigned int*)(hb + (size_t)e0.x * D_OUT + lane * 2);
        unsigned int h1 = *(const unsigned int*)(hb + (size_t)e1.x * D_OUT + lane * 2);
        unsigned int h2 = *(const unsigned int*)(hb + (size_t)e2.x * D_OUT + lane * 2);
        unsigned int h3 = *(const unsigned int*)(hb + (size_t)e3.x * D_OUT + lane * 2);
        float v0 = __builtin_bit_cast(float, e0.y);
        float v1 = __builtin_bit_cast(float, e1.y);
        float v2 = __builtin_bit_cast(float, e2.y);
        float v3 = __builtin_bit_cast(float, e3.y);
        ax0 = fmaf(v0, bf_lo(h0), ax0); ay0 = fmaf(v0, bf_hi(h0), ay0);
        ax1 = fmaf(v1, bf_lo(h1), ax1); ay1 = fmaf(v1, bf_hi(h1), ay1);
        ax2 = fmaf(v2, bf_lo(h2), ax2); ay2 = fmaf(v2, bf_hi(h2), ay2);
        ax3 = fmaf(v3, bf_lo(h3), ax3); ay3 = fmaf(v3, bf_hi(h3), ay3);
    }
    for (; j < end; ++j) {
        int2 e = edge_r[j];
        unsigned int h = *(const unsigned int*)(hb + (size_t)e.x * D_OUT + lane * 2);
        float v = __builtin_bit_cast(float, e.y);
        ax0 = fmaf(v, bf_lo(h), ax0);
        ay0 = fmaf(v, bf_hi(h), ay0);
    }
    float accx = (ax0 + ax1) + (ax2 + ax3);
    float accy = (ay0 + ay1) + (ay2 + ay3);
    float2 o = make_float2(fmaxf(accx, 0.f), fmaxf(accy, 0.f));
    *(float2*)(out + (size_t)row * D_OUT + lane * 2) = o;
}

extern "C" void kernel_launch(void* const* d_in, const int* in_sizes, int n_in,
                              void* d_out, int out_size, void* d_ws, size_t ws_size,
                              hipStream_t stream) {
    const float* x    = (const float*)d_in[0];
    const float* W    = (const float*)d_in[1];
    const int*   rows = (const int*)d_in[2];
    const int*   cols = (const int*)d_in[3];
    const float* vals = (const float*)d_in[4];
    float* out = (float*)d_out;

    // workspace layout (~39.3 MB)
    char* ws = (char*)d_ws;
    size_t off = 0;
    unsigned short* hb  = (unsigned short*)(ws + off); off += ((size_t)N_NODES * D_OUT * 2 + 255) & ~(size_t)255;
    unsigned short* WbT = (unsigned short*)(ws + off); off += ((size_t)D_IN * D_OUT * 2 + 255) & ~(size_t)255;
    int*  ptr    = (int*)(ws + off); off += ((size_t)(N_NODES + 1) * 4 + 255) & ~(size_t)255;
    int*  cursor = (int*)(ws + off); off += ((size_t)N_NODES * 4 + 255) & ~(size_t)255;
    int2* edge_r = (int2*)(ws + off); off += ((size_t)N_EDGES * 8 + 255) & ~(size_t)255;
    int*  bsum   = (int*)(ws + off); off += 4096;

    const int nscan = (N_NODES + SCHUNK - 1) / SCHUNK;  // 98

    convert_w<<<(D_IN * D_OUT) / 256, 256, 0, stream>>>(W, WbT);
    gemm_mfma<<<(N_NODES + 127) / 128, 256, 0, stream>>>(x, WbT, hb);

    hipMemsetAsync(cursor, 0, (size_t)N_NODES * 4, stream);
    hist_rows<<<(N_EDGES / 4 + 255) / 256, 256, 0, stream>>>(rows, cursor);
    scan_reduce<<<nscan, 1024, 0, stream>>>(cursor, bsum, N_NODES);
    scan_bsums<<<1, 64, 0, stream>>>(bsum, nscan);
    scan_apply<<<nscan, 1024, 0, stream>>>(cursor, bsum, ptr, cursor, N_NODES);
    permute_edges<<<(N_EDGES + 255) / 256, 256, 0, stream>>>(rows, cols, vals, cursor, edge_r);

    gather_rows<<<(N_NODES + 3) / 4, 256, 0, stream>>>(ptr, edge_r, hb, out);
}